// Round 9
// baseline (248.323 us; speedup 1.0000x reference)
//
#include <hip/hip_runtime.h>
#include <math.h>

// Problem constants
#define Bsz 64
#define Nn 512
#define Ff 128
#define Hh 256
#define OUTD 6
#define MTOT (Bsz * Nn)   // 32768

typedef __bf16 bf16x8 __attribute__((ext_vector_type(8)));
typedef float f32x4 __attribute__((ext_vector_type(4)));
typedef int int4v __attribute__((ext_vector_type(4)));
typedef unsigned short ushort4v __attribute__((ext_vector_type(4)));

__device__ __forceinline__ unsigned short f2bf(float f) {
    unsigned u = __float_as_uint(f);
    u += 0x7FFFu + ((u >> 16) & 1u);        // RNE
    return (unsigned short)(u >> 16);
}
__device__ __forceinline__ float bf2f(unsigned short s) {
    return __uint_as_float(((unsigned)s) << 16);
}

// XOR swizzle of the 16B k-chunk within a 64B LDS row (kills ds_read_b128 bank conflicts)
#define SWZ(r) (((r) ^ ((r) >> 2)) & 3)

// async 16B global->LDS (DMA; LDS dest = wave-uniform base + lane*16)
__device__ __forceinline__ void async_ld16(const unsigned short* g, unsigned short* l) {
    __builtin_amdgcn_global_load_lds(
        (const __attribute__((address_space(1))) void*)g,
        (__attribute__((address_space(3))) void*)l,
        16, 0, 0);
}

#define LDH 40           // padded LDS row stride (bf16) for the non-async h0 kernel
#define TSZ (128 * 32)   // one LDS tile: 128 rows x 32 bf16 (8 KB)

// ---------------- bf16 MFMA GEMM, 128x128 tile, 8 waves, dbuf, fused 2nd pair ------
// out = act( A0@B0 [+ A1@B1] + bias ); B operands TRANSPOSED (BT[n][k]); row stride == K.
// flags&1 = relu; flags&8 = decode 1D grid (graph = id&63 -> XCD locality).
// CT (optional) = transposed copy [graph][n][node].
__global__ __launch_bounds__(512) void gemm_bf16(
    const unsigned short* __restrict__ A0, const unsigned short* __restrict__ B0T,
    const unsigned short* __restrict__ A1, const unsigned short* __restrict__ B1T,
    const float* __restrict__ bias,
    unsigned short* __restrict__ C, unsigned short* __restrict__ CT,
    int M, int Ntot, int K0, int K1,
    long strideA0, long strideB0, long strideC, int flags)
{
    int bx, by, bz;
    if (flags & 8) {
        int id = blockIdx.x;
        bz = id & 63;
        int t = id >> 6;
        bx = t & 3;
        by = t >> 2;
    } else { bx = blockIdx.x; by = blockIdx.y; bz = blockIdx.z; }

    A0 += (long)bz * strideA0;
    B0T += (long)bz * strideB0;
    C += (long)bz * strideC;

    __shared__ unsigned short As[2 * TSZ];   // double-buffered, 64B rows, swizzled chunks
    __shared__ unsigned short Bs[2 * TSZ];

    int tid = threadIdx.x;
    int lane = tid & 63;
    int wave = tid >> 6;                 // 0..7
    int quad = lane >> 4, l16 = lane & 15;
    int wm = (wave >> 1) * 32, wn = (wave & 1) * 64;   // 32x64 per wave
    int m0 = bx * 128, n0 = by * 128;

    int sr = lane >> 2;        // staging row within 16-row group
    int sc = lane & 3;         // staging chunk slot

    int T0 = K0 >> 5, T1 = K1 >> 5;
    int T = T0 + T1;

    f32x4 acc[2][4] = {};

    // issue tile g's staging loads into buffer (g&1); each wave stages 16 rows of A + B
    auto issue = [&](int g) {
        const unsigned short* Ag; const unsigned short* Bg; int Kg, kk;
        if (g < T0) { Ag = A0; Bg = B0T; Kg = K0; kk = g << 5; }
        else        { Ag = A1; Bg = B1T; Kg = K1; kk = (g - T0) << 5; }
        unsigned short* Ad = As + (g & 1) * TSZ;
        unsigned short* Bd = Bs + (g & 1) * TSZ;
        int r = wave * 16 + sr;
        int c = sc ^ SWZ(r);
        async_ld16(Ag + (long)(m0 + r) * Kg + kk + c * 8, Ad + (wave * 16) * 32);
        async_ld16(Bg + (long)(n0 + r) * Kg + kk + c * 8, Bd + (wave * 16) * 32);
    };

    issue(0);
    for (int g = 0; g < T; ++g) {
        __syncthreads();                      // drains tile g's loads (issued last iter)
        if (g + 1 < T) issue(g + 1);          // overlaps with compute of tile g
        const unsigned short* Ab = As + (g & 1) * TSZ;
        const unsigned short* Bb = Bs + (g & 1) * TSZ;
        bf16x8 af[2], bfr[4];
        #pragma unroll
        for (int i = 0; i < 2; ++i) {
            int r = wm + i * 16 + l16;
            af[i] = *(const bf16x8*)&Ab[r * 32 + (quad ^ SWZ(r)) * 8];
        }
        #pragma unroll
        for (int j = 0; j < 4; ++j) {
            int r = wn + j * 16 + l16;
            bfr[j] = *(const bf16x8*)&Bb[r * 32 + (quad ^ SWZ(r)) * 8];
        }
        #pragma unroll
        for (int i = 0; i < 2; ++i)
            #pragma unroll
            for (int j = 0; j < 4; ++j)
                acc[i][j] = __builtin_amdgcn_mfma_f32_16x16x32_bf16(
                    af[i], bfr[j], acc[i][j], 0, 0, 0);
    }

    // ---- epilogue. C/D layout: col = lane&15, row = quad*4 + reg ----
    int ldc = Ntot;
    #pragma unroll
    for (int i = 0; i < 2; ++i) {
        int mb = m0 + wm + i * 16 + quad * 4;
        #pragma unroll
        for (int j = 0; j < 4; ++j) {
            int n = n0 + wn + j * 16 + l16;
            f32x4 v = acc[i][j];
            float bv = bias ? bias[n] : 0.0f;
            float o0 = v[0] + bv, o1 = v[1] + bv, o2 = v[2] + bv, o3 = v[3] + bv;
            if (flags & 1) {
                o0 = fmaxf(o0, 0.f); o1 = fmaxf(o1, 0.f);
                o2 = fmaxf(o2, 0.f); o3 = fmaxf(o3, 0.f);
            }
            unsigned short s0 = f2bf(o0), s1 = f2bf(o1), s2 = f2bf(o2), s3 = f2bf(o3);
            C[(long)(mb + 0) * ldc + n] = s0;
            C[(long)(mb + 1) * ldc + n] = s1;
            C[(long)(mb + 2) * ldc + n] = s2;
            C[(long)(mb + 3) * ldc + n] = s3;
            if (CT) {
                ushort4v p; p[0] = s0; p[1] = s1; p[2] = s2; p[3] = s3;
                long ti = ((long)(mb >> 9) * Ntot + n) * 512 + (mb & 511);
                *(ushort4v*)&CT[ti] = p;
            }
        }
    }
}

// ---------------- prep: weight convert/transpose + w zero + h0 MFMA ------------
// blocks [0, 960): convert branch; blocks [960, 1216): h0 (m0 = (blk-960)*128)
__global__ __launch_bounds__(256) void prep_h0(
    const float* __restrict__ x, const float* __restrict__ Wg,
    const float* __restrict__ bg,
    const float* __restrict__ Wrel0, const float* __restrict__ Wroot0,
    const float* __restrict__ Wrel1, const float* __restrict__ Wroot1,
    unsigned short* __restrict__ T0, unsigned short* __restrict__ T1,
    unsigned short* __restrict__ T2, unsigned short* __restrict__ T3,
    unsigned short* __restrict__ WgT,
    float* __restrict__ w,
    unsigned short* __restrict__ h0b, unsigned short* __restrict__ h0T,
    float* __restrict__ sqv)
{
    if (blockIdx.x < 960) {
        int idx = blockIdx.x * 256 + threadIdx.x;    // 0..245759
        if (idx >= 212992) { w[idx - 212992] = 0.f; return; }    // w: 32768 floats
        if (idx >= 196608) {                          // WgT: [128 out][128 in]
            int e = idx - 196608;
            int o = e >> 7, i = e & 127;
            WgT[e] = f2bf(Wg[(long)i * 128 + o]);
            return;
        }
        const float* src; unsigned short* dst; int kin; int e;
        if      (idx <  32768) { src = Wrel0;  dst = T0; kin = 128; e = idx; }
        else if (idx <  65536) { src = Wroot0; dst = T1; kin = 128; e = idx - 32768; }
        else if (idx < 131072) { src = Wrel1;  dst = T2; kin = 256; e = idx - 65536; }
        else                   { src = Wroot1; dst = T3; kin = 256; e = idx - 131072; }
        int o = (kin == 128) ? (e >> 7) : (e >> 8);
        int i = e & (kin - 1);
        dst[e] = f2bf(src[(long)i * 256 + o]);       // conv out-dims are all 256
        return;
    }

    // ---- h0 branch (WgT prepared in a loop iteration BEFORE this kernel? no —
    // WgT is produced by convert blocks of THIS kernel; h0 must not depend on it.
    // So h0 converts Wg rows itself while staging (same as x staging). ----
    __shared__ unsigned short As[128 * LDH];
    __shared__ unsigned short Bs[128 * LDH];
    __shared__ float rsq[128];

    int tid = threadIdx.x;
    int lane = tid & 63;
    int wave = tid >> 6;
    int quad = lane >> 4, l16 = lane & 15;
    int wm = (wave >> 1) * 64, wn = (wave & 1) * 64;
    int m0 = (blockIdx.x - 960) * 128;

    f32x4 acc[4][4] = {};

    for (int k0 = 0; k0 < Ff; k0 += 32) {
        __syncthreads();
        #pragma unroll
        for (int l = 0; l < 2; ++l) {
            int idx = tid + l * 256;
            int r = idx >> 2, ch = idx & 3;
            const float* px = x + (long)(m0 + r) * Ff + k0 + ch * 8;
            float4 xa = *(const float4*)px;
            float4 xb = *(const float4*)(px + 4);
            ushort4v pa, pb;
            pa[0] = f2bf(xa.x); pa[1] = f2bf(xa.y); pa[2] = f2bf(xa.z); pa[3] = f2bf(xa.w);
            pb[0] = f2bf(xb.x); pb[1] = f2bf(xb.y); pb[2] = f2bf(xb.z); pb[3] = f2bf(xb.w);
            *(ushort4v*)&As[r * LDH + ch * 8] = pa;
            *(ushort4v*)&As[r * LDH + ch * 8 + 4] = pb;
            // B = WgT[r][k] = Wg[k][r] (transpose on the fly, fp32 source)
            int kk = k0 + ch * 8;
            ushort4v qa, qb;
            #pragma unroll
            for (int u = 0; u < 4; ++u) qa[u] = f2bf(Wg[(long)(kk + u) * 128 + r]);
            #pragma unroll
            for (int u = 0; u < 4; ++u) qb[u] = f2bf(Wg[(long)(kk + 4 + u) * 128 + r]);
            *(ushort4v*)&Bs[r * LDH + ch * 8] = qa;
            *(ushort4v*)&Bs[r * LDH + ch * 8 + 4] = qb;
        }
        __syncthreads();
        bf16x8 af[4], bfr[4];
        #pragma unroll
        for (int i = 0; i < 4; ++i)
            af[i] = *(const bf16x8*)&As[(wm + i * 16 + l16) * LDH + quad * 8];
        #pragma unroll
        for (int j = 0; j < 4; ++j)
            bfr[j] = *(const bf16x8*)&Bs[(wn + j * 16 + l16) * LDH + quad * 8];
        #pragma unroll
        for (int i = 0; i < 4; ++i)
            #pragma unroll
            for (int j = 0; j < 4; ++j)
                acc[i][j] = __builtin_amdgcn_mfma_f32_16x16x32_bf16(
                    af[i], bfr[j], acc[i][j], 0, 0, 0);
    }

    if (tid < 128) rsq[tid] = 0.f;
    __syncthreads();

    #pragma unroll
    for (int i = 0; i < 4; ++i) {
        int lrow = wm + i * 16 + quad * 4;   // local row of first of 4
        int mb = m0 + lrow;
        float rp0 = 0.f, rp1 = 0.f, rp2 = 0.f, rp3 = 0.f;
        #pragma unroll
        for (int j = 0; j < 4; ++j) {
            int n = wn + j * 16 + l16;
            f32x4 v = acc[i][j];
            float bv = bg[n];
            unsigned short s0 = f2bf(v[0] + bv), s1 = f2bf(v[1] + bv);
            unsigned short s2 = f2bf(v[2] + bv), s3 = f2bf(v[3] + bv);
            h0b[(long)(mb + 0) * Ff + n] = s0;
            h0b[(long)(mb + 1) * Ff + n] = s1;
            h0b[(long)(mb + 2) * Ff + n] = s2;
            h0b[(long)(mb + 3) * Ff + n] = s3;
            ushort4v p; p[0] = s0; p[1] = s1; p[2] = s2; p[3] = s3;
            long ti = ((long)(mb >> 9) * Ff + n) * 512 + (mb & 511);
            *(ushort4v*)&h0T[ti] = p;
            float f0 = bf2f(s0), f1 = bf2f(s1), f2 = bf2f(s2), f3 = bf2f(s3);
            rp0 += f0 * f0; rp1 += f1 * f1; rp2 += f2 * f2; rp3 += f3 * f3;
        }
        #pragma unroll
        for (int m = 1; m < 16; m <<= 1) {
            rp0 += __shfl_xor(rp0, m);
            rp1 += __shfl_xor(rp1, m);
            rp2 += __shfl_xor(rp2, m);
            rp3 += __shfl_xor(rp3, m);
        }
        if (l16 == 0) {   // two waves share rows -> atomic
            atomicAdd(&rsq[lrow + 0], rp0);
            atomicAdd(&rsq[lrow + 1], rp1);
            atomicAdd(&rsq[lrow + 2], rp2);
            atomicAdd(&rsq[lrow + 3], rp3);
        }
    }
    __syncthreads();
    if (tid < 128) sqv[m0 + tid] = rsq[tid];
}

// ---------------- Gram -> adjacency A via MFMA (8 waves, dbuf; also row-sums w) -----
// 1D grid: graph = id&63, tile = id>>6 (x = t&3, y = t>>2) — XCD locality.
// A store is TRANSPOSED-packed: A symmetric and tile math is bitwise symmetric,
// so *(ushort4*)&A[c][rb] == the 4 scattered stores of A[rb..rb+3][c].
__global__ __launch_bounds__(512) void gram_A_mfma(
    const unsigned short* __restrict__ h0b, const float* __restrict__ sqv,
    const float* __restrict__ sigma, unsigned short* __restrict__ Aout,
    float* __restrict__ w)
{
    int id = blockIdx.x;
    int b = id & 63;
    int t = id >> 6;
    int i0 = (t & 3) * 128, j0 = (t >> 2) * 128;

    const unsigned short* H = h0b + (long)b * Nn * Ff;
    const float* SQ = sqv + (long)b * Nn;
    unsigned short* Ab = Aout + (long)b * Nn * Nn;

    __shared__ unsigned short Is[2 * TSZ];
    __shared__ unsigned short Js[2 * TSZ];
    __shared__ float rsum[128];

    int tid = threadIdx.x;
    int lane = tid & 63;
    int wave = tid >> 6;                 // 0..7
    int quad = lane >> 4, l16 = lane & 15;
    int wm = (wave >> 1) * 32, wn = (wave & 1) * 64;

    int sr = lane >> 2, sc = lane & 3;

    f32x4 acc[2][4] = {};

    auto issue = [&](int g) {
        int kk = g << 5;
        unsigned short* Id = Is + (g & 1) * TSZ;
        unsigned short* Jd = Js + (g & 1) * TSZ;
        int r = wave * 16 + sr;
        int c = sc ^ SWZ(r);
        async_ld16(H + (long)(i0 + r) * Ff + kk + c * 8, Id + (wave * 16) * 32);
        async_ld16(H + (long)(j0 + r) * Ff + kk + c * 8, Jd + (wave * 16) * 32);
    };

    issue(0);
    for (int g = 0; g < (Ff >> 5); ++g) {
        __syncthreads();
        if (g + 1 < (Ff >> 5)) issue(g + 1);
        const unsigned short* Ib = Is + (g & 1) * TSZ;
        const unsigned short* Jb = Js + (g & 1) * TSZ;
        bf16x8 af[2], bfr[4];
        #pragma unroll
        for (int i = 0; i < 2; ++i) {
            int r = wm + i * 16 + l16;
            af[i] = *(const bf16x8*)&Ib[r * 32 + (quad ^ SWZ(r)) * 8];
        }
        #pragma unroll
        for (int j = 0; j < 4; ++j) {
            int r = wn + j * 16 + l16;
            bfr[j] = *(const bf16x8*)&Jb[r * 32 + (quad ^ SWZ(r)) * 8];
        }
        #pragma unroll
        for (int i = 0; i < 2; ++i)
            #pragma unroll
            for (int j = 0; j < 4; ++j)
                acc[i][j] = __builtin_amdgcn_mfma_f32_16x16x32_bf16(
                    af[i], bfr[j], acc[i][j], 0, 0, 0);
    }

    if (tid < 128) rsum[tid] = 0.f;
    __syncthreads();

    float s = sigma[0];
    float inv2s2 = 1.0f / (2.0f * s * s);
    #pragma unroll
    for (int i = 0; i < 2; ++i) {
        int lrow = wm + i * 16 + quad * 4;
        int rb = i0 + lrow;
        float rs0 = 0.f, rs1 = 0.f, rs2 = 0.f, rs3 = 0.f;
        #pragma unroll
        for (int j = 0; j < 4; ++j) {
            int c = j0 + wn + j * 16 + l16;
            float sqc = SQ[c];
            f32x4 v = acc[i][j];
            ushort4v pk;
            float av[4];
            #pragma unroll
            for (int r4 = 0; r4 < 4; ++r4) {
                int r = rb + r4;
                float d = fmaxf(SQ[r] + sqc - 2.0f * v[r4], 0.0f);
                unsigned short a = (r == c) ? (unsigned short)0
                                            : f2bf(__expf(-d * inv2s2));
                pk[r4] = a;
                av[r4] = bf2f(a);
            }
            // transposed packed store (A symmetric; bitwise identical to direct store)
            *(ushort4v*)&Ab[(long)c * Nn + rb] = pk;
            rs0 += av[0]; rs1 += av[1]; rs2 += av[2]; rs3 += av[3];
        }
        #pragma unroll
        for (int m = 1; m < 16; m <<= 1) {
            rs0 += __shfl_xor(rs0, m);
            rs1 += __shfl_xor(rs1, m);
            rs2 += __shfl_xor(rs2, m);
            rs3 += __shfl_xor(rs3, m);
        }
        if (l16 == 0) {
            atomicAdd(&rsum[lrow + 0], rs0);
            atomicAdd(&rsum[lrow + 1], rs1);
            atomicAdd(&rsum[lrow + 2], rs2);
            atomicAdd(&rsum[lrow + 3], rs3);
        }
    }
    __syncthreads();
    if (tid < 128) atomicAdd(&w[(long)b * Nn + i0 + tid], rsum[tid]);
}

// ---------------- pool + head (one block per graph) ----------------
// v[c] = sum_j w[j]*h2[j][c]; m[c] = sum_j h2[j][c];
// g = (v/N)@Wrel2 + (m/N)@Wroot2 + brel2; out = relu(g@W1+b1)@Wout + bout
__global__ __launch_bounds__(512) void pool_head(
    const unsigned short* __restrict__ h2b, const float* __restrict__ w,
    const float* __restrict__ Wrel2, const float* __restrict__ Wroot2,
    const float* __restrict__ brel2,
    const float* __restrict__ W1, const float* __restrict__ b1,
    const float* __restrict__ Wout, const float* __restrict__ bout,
    float* __restrict__ out)
{
    int b = blockIdx.x;
    int tid = threadIdx.x;
    int c = tid & 255;          // feature
    int half = tid >> 8;        // node half (0/1)

    __shared__ float vs[2][Hh], ms[2][Hh];
    __shared__ float gs[Hh], g2[Hh];

    const unsigned short* H = h2b + ((long)b * Nn + half * 256) * Hh + c;
    const float* wp = w + (long)b * Nn + half * 256;
    float vp = 0.f, mp = 0.f;
    #pragma unroll 4
    for (int j = 0; j < 256; ++j) {
        float val = bf2f(H[(long)j * Hh]);
        mp += val;
        vp += wp[j] * val;
    }
    vs[half][c] = vp;
    ms[half][c] = mp;
    __syncthreads();

    if (tid < Hh) {
        int j = tid;
        float vj, mj;
        // re-read per-feature sums (note: vs/ms indexed by feature j)
        vj = (vs[0][j] + vs[1][j]) * (1.0f / (float)Nn);
        mj = (ms[0][j] + ms[1][j]) * (1.0f / (float)Nn);
        gs[j] = vj;  g2[j] = mj;   // stash scaled sums
    }
    __syncthreads();
    float g_j = 0.f;
    if (tid < Hh) {
        int j = tid;
        float s = brel2[j];
        for (int cc = 0; cc < Hh; ++cc)
            s += gs[cc] * Wrel2[cc * Hh + j] + g2[cc] * Wroot2[cc * Hh + j];
        g_j = s;
    }
    __syncthreads();
    if (tid < Hh) gs[tid] = g_j;
    __syncthreads();
    if (tid < Hh) {
        int j = tid;
        float t = b1[j];
        for (int k = 0; k < Hh; ++k) t += gs[k] * W1[k * Hh + j];
        g2[j] = fmaxf(t, 0.f);
    }
    __syncthreads();
    if (tid < OUTD) {
        int j = tid;
        float s2 = bout[j];
        for (int k = 0; k < Hh; ++k) s2 += g2[k] * Wout[k * OUTD + j];
        out[b * OUTD + j] = s2;
    }
}

extern "C" void kernel_launch(void* const* d_in, const int* in_sizes, int n_in,
                              void* d_out, int out_size, void* d_ws, size_t ws_size,
                              hipStream_t stream) {
    const float* x      = (const float*)d_in[0];
    const float* sigma  = (const float*)d_in[4];
    const float* Wg     = (const float*)d_in[5];
    const float* bg     = (const float*)d_in[6];
    const float* Wrel0  = (const float*)d_in[7];
    const float* Wroot0 = (const float*)d_in[8];
    const float* brel0  = (const float*)d_in[9];
    const float* Wrel1  = (const float*)d_in[10];
    const float* Wroot1 = (const float*)d_in[11];
    const float* brel1  = (const float*)d_in[12];
    const float* Wrel2  = (const float*)d_in[13];
    const float* Wroot2 = (const float*)d_in[14];
    const float* brel2  = (const float*)d_in[15];
    const float* W1     = (const float*)d_in[16];
    const float* b1     = (const float*)d_in[17];
    const float* Wout   = (const float*)d_in[18];
    const float* bout   = (const float*)d_in[19];
    float* out = (float*)d_out;

    // Workspace layout (bytes)
    char* ws = (char*)d_ws;
    unsigned short* WgT  = (unsigned short*)(ws + 0);              // 32 KB
    unsigned short* h0b  = (unsigned short*)(ws + 16777216);       // 8 MB
    unsigned short* h0T  = (unsigned short*)(ws + 25165824);       // 8 MB
    float*          sq   = (float*)(ws + 33554432);                // 128 KB
    unsigned short* Aadj = (unsigned short*)(ws + 33685504);       // 32 MB
    unsigned short* agg  = (unsigned short*)(ws + 67239936);       // 16 MB
    unsigned short* h1b  = (unsigned short*)(ws + 84017152);       // 16 MB
    unsigned short* h1T  = (unsigned short*)(ws + 100794368);      // 16 MB
    unsigned short* h2b  = (unsigned short*)(ws + 117571584);      // 16 MB
    unsigned short* WrelT0  = (unsigned short*)(ws + 167903232);   // 64 KB
    unsigned short* WrootT0 = (unsigned short*)(ws + 167968768);   // 64 KB
    unsigned short* WrelT1  = (unsigned short*)(ws + 168034304);   // 128 KB
    unsigned short* WrootT1 = (unsigned short*)(ws + 168165376);   // 128 KB
    float*          w    = (float*)(ws + 168558592);               // 128 KB (A row sums)

    // prep (weights + w zero) and h0 in one dispatch
    prep_h0<<<1216, 256, 0, stream>>>(x, Wg, bg, Wrel0, Wroot0, Wrel1, Wroot1,
                                      WrelT0, WrootT0, WrelT1, WrootT1, WgT,
                                      w, h0b, h0T, sq);

    // A = exp(-dist/(2 sigma^2)), zero diag; accumulate row sums w (XCD-swizzled 1D)
    gram_A_mfma<<<dim3(16 * Bsz, 1, 1), 512, 0, stream>>>(h0b, sq, sigma, Aadj, w);

    // ---- layer 0 ----
    gemm_bf16<<<dim3(4 * Bsz, 1, 1), 512, 0, stream>>>(
        Aadj, h0T, nullptr, nullptr, nullptr, agg, nullptr,
        Nn, Ff, Nn, 0,
        (long)Nn * Nn, (long)Ff * Nn, (long)Nn * Ff, 8);
    gemm_bf16<<<dim3(MTOT / 128, Hh / 128, 1), 512, 0, stream>>>(
        agg, WrelT0, h0b, WrootT0, brel0, h1b, h1T,
        MTOT, Hh, Ff, Ff, 0, 0, 0, 1);

    // ---- layer 1 ----
    gemm_bf16<<<dim3(8 * Bsz, 1, 1), 512, 0, stream>>>(
        Aadj, h1T, nullptr, nullptr, nullptr, agg, nullptr,
        Nn, Hh, Nn, 0,
        (long)Nn * Nn, (long)Hh * Nn, (long)Nn * Hh, 8);
    gemm_bf16<<<dim3(MTOT / 128, Hh / 128, 1), 512, 0, stream>>>(
        agg, WrelT1, h1b, WrootT1, brel1, h2b, nullptr,
        MTOT, Hh, Hh, Hh, 0, 0, 0, 1);

    // ---- layer 2 collapsed + pool + head (one dispatch) ----
    pool_head<<<Bsz, 512, 0, stream>>>(h2b, w, Wrel2, Wroot2, brel2,
                                       W1, b1, Wout, bout, out);
}

// Round 10
// 236.385 us; speedup vs baseline: 1.0505x; 1.0505x over previous
//
#include <hip/hip_runtime.h>
#include <math.h>

// Problem constants
#define Bsz 64
#define Nn 512
#define Ff 128
#define Hh 256
#define OUTD 6
#define MTOT (Bsz * Nn)   // 32768

typedef __bf16 bf16x8 __attribute__((ext_vector_type(8)));
typedef float f32x4 __attribute__((ext_vector_type(4)));
typedef int int4v __attribute__((ext_vector_type(4)));
typedef unsigned short ushort4v __attribute__((ext_vector_type(4)));

__device__ __forceinline__ unsigned short f2bf(float f) {
    unsigned u = __float_as_uint(f);
    u += 0x7FFFu + ((u >> 16) & 1u);        // RNE
    return (unsigned short)(u >> 16);
}
__device__ __forceinline__ float bf2f(unsigned short s) {
    return __uint_as_float(((unsigned)s) << 16);
}

// XOR swizzle of the 16B k-chunk within a 64B LDS row (kills ds_read_b128 bank conflicts)
#define SWZ(r) (((r) ^ ((r) >> 2)) & 3)

// async 16B global->LDS (DMA; LDS dest = wave-uniform base + lane*16)
__device__ __forceinline__ void async_ld16(const unsigned short* g, unsigned short* l) {
    __builtin_amdgcn_global_load_lds(
        (const __attribute__((address_space(1))) void*)g,
        (__attribute__((address_space(3))) void*)l,
        16, 0, 0);
}

#define LDH 40           // padded LDS row stride (bf16) for the non-async h0 kernel
#define TSZ (128 * 32)   // one LDS tile: 128 rows x 32 bf16 (8 KB)

// ---------------- bf16 MFMA GEMM, 128x128 tile, 8 waves, dbuf, fused 2nd pair ------
// out = act( A0@B0 [+ A1@B1] + bias ); B operands TRANSPOSED (BT[n][k]); row stride == K.
// flags&1 = relu; flags&8 = decode 1D grid (graph = id&63 -> XCD locality).
// CT (optional) = transposed copy [graph][n][node].
__global__ __launch_bounds__(512) void gemm_bf16(
    const unsigned short* __restrict__ A0, const unsigned short* __restrict__ B0T,
    const unsigned short* __restrict__ A1, const unsigned short* __restrict__ B1T,
    const float* __restrict__ bias,
    unsigned short* __restrict__ C, unsigned short* __restrict__ CT,
    int M, int Ntot, int K0, int K1,
    long strideA0, long strideB0, long strideC, int flags)
{
    int bx, by, bz;
    if (flags & 8) {
        int id = blockIdx.x;
        bz = id & 63;
        int t = id >> 6;
        bx = t & 3;
        by = t >> 2;
    } else { bx = blockIdx.x; by = blockIdx.y; bz = blockIdx.z; }

    A0 += (long)bz * strideA0;
    B0T += (long)bz * strideB0;
    C += (long)bz * strideC;

    __shared__ unsigned short As[2 * TSZ];   // double-buffered, 64B rows, swizzled chunks
    __shared__ unsigned short Bs[2 * TSZ];

    int tid = threadIdx.x;
    int lane = tid & 63;
    int wave = tid >> 6;                 // 0..7
    int quad = lane >> 4, l16 = lane & 15;
    int wm = (wave >> 1) * 32, wn = (wave & 1) * 64;   // 32x64 per wave
    int m0 = bx * 128, n0 = by * 128;

    int sr = lane >> 2;        // staging row within 16-row group
    int sc = lane & 3;         // staging chunk slot

    int T0 = K0 >> 5, T1 = K1 >> 5;
    int T = T0 + T1;

    f32x4 acc[2][4] = {};

    // issue tile g's staging loads into buffer (g&1); each wave stages 16 rows of A + B
    auto issue = [&](int g) {
        const unsigned short* Ag; const unsigned short* Bg; int Kg, kk;
        if (g < T0) { Ag = A0; Bg = B0T; Kg = K0; kk = g << 5; }
        else        { Ag = A1; Bg = B1T; Kg = K1; kk = (g - T0) << 5; }
        unsigned short* Ad = As + (g & 1) * TSZ;
        unsigned short* Bd = Bs + (g & 1) * TSZ;
        int r = wave * 16 + sr;
        int c = sc ^ SWZ(r);
        async_ld16(Ag + (long)(m0 + r) * Kg + kk + c * 8, Ad + (wave * 16) * 32);
        async_ld16(Bg + (long)(n0 + r) * Kg + kk + c * 8, Bd + (wave * 16) * 32);
    };

    issue(0);
    for (int g = 0; g < T; ++g) {
        __syncthreads();                      // drains tile g's loads (issued last iter)
        if (g + 1 < T) issue(g + 1);          // overlaps with compute of tile g
        const unsigned short* Ab = As + (g & 1) * TSZ;
        const unsigned short* Bb = Bs + (g & 1) * TSZ;
        bf16x8 af[2], bfr[4];
        #pragma unroll
        for (int i = 0; i < 2; ++i) {
            int r = wm + i * 16 + l16;
            af[i] = *(const bf16x8*)&Ab[r * 32 + (quad ^ SWZ(r)) * 8];
        }
        #pragma unroll
        for (int j = 0; j < 4; ++j) {
            int r = wn + j * 16 + l16;
            bfr[j] = *(const bf16x8*)&Bb[r * 32 + (quad ^ SWZ(r)) * 8];
        }
        #pragma unroll
        for (int i = 0; i < 2; ++i)
            #pragma unroll
            for (int j = 0; j < 4; ++j)
                acc[i][j] = __builtin_amdgcn_mfma_f32_16x16x32_bf16(
                    af[i], bfr[j], acc[i][j], 0, 0, 0);
    }

    // ---- epilogue. C/D layout: col = lane&15, row = quad*4 + reg ----
    int ldc = Ntot;
    #pragma unroll
    for (int i = 0; i < 2; ++i) {
        int mb = m0 + wm + i * 16 + quad * 4;
        #pragma unroll
        for (int j = 0; j < 4; ++j) {
            int n = n0 + wn + j * 16 + l16;
            f32x4 v = acc[i][j];
            float bv = bias ? bias[n] : 0.0f;
            float o0 = v[0] + bv, o1 = v[1] + bv, o2 = v[2] + bv, o3 = v[3] + bv;
            if (flags & 1) {
                o0 = fmaxf(o0, 0.f); o1 = fmaxf(o1, 0.f);
                o2 = fmaxf(o2, 0.f); o3 = fmaxf(o3, 0.f);
            }
            unsigned short s0 = f2bf(o0), s1 = f2bf(o1), s2 = f2bf(o2), s3 = f2bf(o3);
            C[(long)(mb + 0) * ldc + n] = s0;
            C[(long)(mb + 1) * ldc + n] = s1;
            C[(long)(mb + 2) * ldc + n] = s2;
            C[(long)(mb + 3) * ldc + n] = s3;
            if (CT) {
                ushort4v p; p[0] = s0; p[1] = s1; p[2] = s2; p[3] = s3;
                long ti = ((long)(mb >> 9) * Ntot + n) * 512 + (mb & 511);
                *(ushort4v*)&CT[ti] = p;
            }
        }
    }
}

// ---------------- prep: weight convert/transpose + w zero + h0 MFMA ------------
// blocks [0, 960): convert branch; blocks [960, 1216): h0 (m0 = (blk-960)*128)
__global__ __launch_bounds__(256) void prep_h0(
    const float* __restrict__ x, const float* __restrict__ Wg,
    const float* __restrict__ bg,
    const float* __restrict__ Wrel0, const float* __restrict__ Wroot0,
    const float* __restrict__ Wrel1, const float* __restrict__ Wroot1,
    unsigned short* __restrict__ T0, unsigned short* __restrict__ T1,
    unsigned short* __restrict__ T2, unsigned short* __restrict__ T3,
    unsigned short* __restrict__ WgT,
    float* __restrict__ w,
    unsigned short* __restrict__ h0b, unsigned short* __restrict__ h0T,
    float* __restrict__ sqv)
{
    if (blockIdx.x < 960) {
        int idx = blockIdx.x * 256 + threadIdx.x;    // 0..245759
        if (idx >= 212992) { w[idx - 212992] = 0.f; return; }    // w: 32768 floats
        if (idx >= 196608) {                          // WgT: [128 out][128 in]
            int e = idx - 196608;
            int o = e >> 7, i = e & 127;
            WgT[e] = f2bf(Wg[(long)i * 128 + o]);
            return;
        }
        const float* src; unsigned short* dst; int kin; int e;
        if      (idx <  32768) { src = Wrel0;  dst = T0; kin = 128; e = idx; }
        else if (idx <  65536) { src = Wroot0; dst = T1; kin = 128; e = idx - 32768; }
        else if (idx < 131072) { src = Wrel1;  dst = T2; kin = 256; e = idx - 65536; }
        else                   { src = Wroot1; dst = T3; kin = 256; e = idx - 131072; }
        int o = (kin == 128) ? (e >> 7) : (e >> 8);
        int i = e & (kin - 1);
        dst[e] = f2bf(src[(long)i * 256 + o]);       // conv out-dims are all 256
        return;
    }

    // ---- h0 branch: converts Wg on the fly (no dependency on convert blocks) ----
    __shared__ unsigned short As[128 * LDH];
    __shared__ unsigned short Bs[128 * LDH];
    __shared__ float rsq[128];

    int tid = threadIdx.x;
    int lane = tid & 63;
    int wave = tid >> 6;
    int quad = lane >> 4, l16 = lane & 15;
    int wm = (wave >> 1) * 64, wn = (wave & 1) * 64;
    int m0 = (blockIdx.x - 960) * 128;

    f32x4 acc[4][4] = {};

    for (int k0 = 0; k0 < Ff; k0 += 32) {
        __syncthreads();
        #pragma unroll
        for (int l = 0; l < 2; ++l) {
            int idx = tid + l * 256;
            int r = idx >> 2, ch = idx & 3;
            const float* px = x + (long)(m0 + r) * Ff + k0 + ch * 8;
            float4 xa = *(const float4*)px;
            float4 xb = *(const float4*)(px + 4);
            ushort4v pa, pb;
            pa[0] = f2bf(xa.x); pa[1] = f2bf(xa.y); pa[2] = f2bf(xa.z); pa[3] = f2bf(xa.w);
            pb[0] = f2bf(xb.x); pb[1] = f2bf(xb.y); pb[2] = f2bf(xb.z); pb[3] = f2bf(xb.w);
            *(ushort4v*)&As[r * LDH + ch * 8] = pa;
            *(ushort4v*)&As[r * LDH + ch * 8 + 4] = pb;
            // B = WgT[r][k] = Wg[k][r] (transpose on the fly, fp32 source)
            int kk = k0 + ch * 8;
            ushort4v qa, qb;
            #pragma unroll
            for (int u = 0; u < 4; ++u) qa[u] = f2bf(Wg[(long)(kk + u) * 128 + r]);
            #pragma unroll
            for (int u = 0; u < 4; ++u) qb[u] = f2bf(Wg[(long)(kk + 4 + u) * 128 + r]);
            *(ushort4v*)&Bs[r * LDH + ch * 8] = qa;
            *(ushort4v*)&Bs[r * LDH + ch * 8 + 4] = qb;
        }
        __syncthreads();
        bf16x8 af[4], bfr[4];
        #pragma unroll
        for (int i = 0; i < 4; ++i)
            af[i] = *(const bf16x8*)&As[(wm + i * 16 + l16) * LDH + quad * 8];
        #pragma unroll
        for (int j = 0; j < 4; ++j)
            bfr[j] = *(const bf16x8*)&Bs[(wn + j * 16 + l16) * LDH + quad * 8];
        #pragma unroll
        for (int i = 0; i < 4; ++i)
            #pragma unroll
            for (int j = 0; j < 4; ++j)
                acc[i][j] = __builtin_amdgcn_mfma_f32_16x16x32_bf16(
                    af[i], bfr[j], acc[i][j], 0, 0, 0);
    }

    if (tid < 128) rsq[tid] = 0.f;
    __syncthreads();

    #pragma unroll
    for (int i = 0; i < 4; ++i) {
        int lrow = wm + i * 16 + quad * 4;   // local row of first of 4
        int mb = m0 + lrow;
        float rp0 = 0.f, rp1 = 0.f, rp2 = 0.f, rp3 = 0.f;
        #pragma unroll
        for (int j = 0; j < 4; ++j) {
            int n = wn + j * 16 + l16;
            f32x4 v = acc[i][j];
            float bv = bg[n];
            unsigned short s0 = f2bf(v[0] + bv), s1 = f2bf(v[1] + bv);
            unsigned short s2 = f2bf(v[2] + bv), s3 = f2bf(v[3] + bv);
            h0b[(long)(mb + 0) * Ff + n] = s0;
            h0b[(long)(mb + 1) * Ff + n] = s1;
            h0b[(long)(mb + 2) * Ff + n] = s2;
            h0b[(long)(mb + 3) * Ff + n] = s3;
            ushort4v p; p[0] = s0; p[1] = s1; p[2] = s2; p[3] = s3;
            long ti = ((long)(mb >> 9) * Ff + n) * 512 + (mb & 511);
            *(ushort4v*)&h0T[ti] = p;
            float f0 = bf2f(s0), f1 = bf2f(s1), f2 = bf2f(s2), f3 = bf2f(s3);
            rp0 += f0 * f0; rp1 += f1 * f1; rp2 += f2 * f2; rp3 += f3 * f3;
        }
        #pragma unroll
        for (int m = 1; m < 16; m <<= 1) {
            rp0 += __shfl_xor(rp0, m);
            rp1 += __shfl_xor(rp1, m);
            rp2 += __shfl_xor(rp2, m);
            rp3 += __shfl_xor(rp3, m);
        }
        if (l16 == 0) {   // two waves share rows -> atomic
            atomicAdd(&rsq[lrow + 0], rp0);
            atomicAdd(&rsq[lrow + 1], rp1);
            atomicAdd(&rsq[lrow + 2], rp2);
            atomicAdd(&rsq[lrow + 3], rp3);
        }
    }
    __syncthreads();
    if (tid < 128) sqv[m0 + tid] = rsq[tid];
}

// ---------------- Gram -> adjacency A via MFMA (8 waves, dbuf; also row-sums w) -----
// 1D grid: graph = id&63, tile = id>>6 (x = t&3, y = t>>2) — XCD locality.
// A store is TRANSPOSED-packed (A symmetric, bitwise identical).
__global__ __launch_bounds__(512) void gram_A_mfma(
    const unsigned short* __restrict__ h0b, const float* __restrict__ sqv,
    const float* __restrict__ sigma, unsigned short* __restrict__ Aout,
    float* __restrict__ w)
{
    int id = blockIdx.x;
    int b = id & 63;
    int t = id >> 6;
    int i0 = (t & 3) * 128, j0 = (t >> 2) * 128;

    const unsigned short* H = h0b + (long)b * Nn * Ff;
    const float* SQ = sqv + (long)b * Nn;
    unsigned short* Ab = Aout + (long)b * Nn * Nn;

    __shared__ unsigned short Is[2 * TSZ];
    __shared__ unsigned short Js[2 * TSZ];
    __shared__ float rsum[128];

    int tid = threadIdx.x;
    int lane = tid & 63;
    int wave = tid >> 6;                 // 0..7
    int quad = lane >> 4, l16 = lane & 15;
    int wm = (wave >> 1) * 32, wn = (wave & 1) * 64;

    int sr = lane >> 2, sc = lane & 3;

    f32x4 acc[2][4] = {};

    auto issue = [&](int g) {
        int kk = g << 5;
        unsigned short* Id = Is + (g & 1) * TSZ;
        unsigned short* Jd = Js + (g & 1) * TSZ;
        int r = wave * 16 + sr;
        int c = sc ^ SWZ(r);
        async_ld16(H + (long)(i0 + r) * Ff + kk + c * 8, Id + (wave * 16) * 32);
        async_ld16(H + (long)(j0 + r) * Ff + kk + c * 8, Jd + (wave * 16) * 32);
    };

    issue(0);
    for (int g = 0; g < (Ff >> 5); ++g) {
        __syncthreads();
        if (g + 1 < (Ff >> 5)) issue(g + 1);
        const unsigned short* Ib = Is + (g & 1) * TSZ;
        const unsigned short* Jb = Js + (g & 1) * TSZ;
        bf16x8 af[2], bfr[4];
        #pragma unroll
        for (int i = 0; i < 2; ++i) {
            int r = wm + i * 16 + l16;
            af[i] = *(const bf16x8*)&Ib[r * 32 + (quad ^ SWZ(r)) * 8];
        }
        #pragma unroll
        for (int j = 0; j < 4; ++j) {
            int r = wn + j * 16 + l16;
            bfr[j] = *(const bf16x8*)&Jb[r * 32 + (quad ^ SWZ(r)) * 8];
        }
        #pragma unroll
        for (int i = 0; i < 2; ++i)
            #pragma unroll
            for (int j = 0; j < 4; ++j)
                acc[i][j] = __builtin_amdgcn_mfma_f32_16x16x32_bf16(
                    af[i], bfr[j], acc[i][j], 0, 0, 0);
    }

    if (tid < 128) rsum[tid] = 0.f;
    __syncthreads();

    float s = sigma[0];
    float inv2s2 = 1.0f / (2.0f * s * s);
    #pragma unroll
    for (int i = 0; i < 2; ++i) {
        int lrow = wm + i * 16 + quad * 4;
        int rb = i0 + lrow;
        float rs0 = 0.f, rs1 = 0.f, rs2 = 0.f, rs3 = 0.f;
        #pragma unroll
        for (int j = 0; j < 4; ++j) {
            int c = j0 + wn + j * 16 + l16;
            float sqc = SQ[c];
            f32x4 v = acc[i][j];
            ushort4v pk;
            float av[4];
            #pragma unroll
            for (int r4 = 0; r4 < 4; ++r4) {
                int r = rb + r4;
                float d = fmaxf(SQ[r] + sqc - 2.0f * v[r4], 0.0f);
                unsigned short a = (r == c) ? (unsigned short)0
                                            : f2bf(__expf(-d * inv2s2));
                pk[r4] = a;
                av[r4] = bf2f(a);
            }
            // transposed packed store (A symmetric; bitwise identical to direct store)
            *(ushort4v*)&Ab[(long)c * Nn + rb] = pk;
            rs0 += av[0]; rs1 += av[1]; rs2 += av[2]; rs3 += av[3];
        }
        #pragma unroll
        for (int m = 1; m < 16; m <<= 1) {
            rs0 += __shfl_xor(rs0, m);
            rs1 += __shfl_xor(rs1, m);
            rs2 += __shfl_xor(rs2, m);
            rs3 += __shfl_xor(rs3, m);
        }
        if (l16 == 0) {
            atomicAdd(&rsum[lrow + 0], rs0);
            atomicAdd(&rsum[lrow + 1], rs1);
            atomicAdd(&rsum[lrow + 2], rs2);
            atomicAdd(&rsum[lrow + 3], rs3);
        }
    }
    __syncthreads();
    if (tid < 128) atomicAdd(&w[(long)b * Nn + i0 + tid], rsum[tid]);
}

// ---------------- partial pool: vpart/mpart[b][chunk][c] (no atomics) ----------
__global__ __launch_bounds__(256) void reduce_h2(
    const unsigned short* __restrict__ h2b, const float* __restrict__ w,
    float* __restrict__ vpart, float* __restrict__ mpart)
{
    int b = blockIdx.x;
    int jc = blockIdx.y;        // 0..7, 64 nodes each
    int c = threadIdx.x;        // 0..255
    const unsigned short* H = h2b + ((long)b * Nn + jc * 64) * Hh + c;
    const float* wp = w + (long)b * Nn + jc * 64;
    float vp = 0.f, mp = 0.f;
    #pragma unroll 4
    for (int j = 0; j < 64; ++j) {
        float val = bf2f(H[(long)j * Hh]);
        mp += val;
        vp += wp[j] * val;
    }
    long o = ((long)b * 8 + jc) * Hh + c;
    vpart[o] = vp;
    mpart[o] = mp;
}

// ---------------- head: sum partials + layer2-collapse + mean + MLP ----------------
__global__ __launch_bounds__(256) void head_kernel(
    const float* __restrict__ vpart, const float* __restrict__ mpart,
    const float* __restrict__ Wrel2, const float* __restrict__ Wroot2,
    const float* __restrict__ brel2,
    const float* __restrict__ W1, const float* __restrict__ b1,
    const float* __restrict__ Wout, const float* __restrict__ bout,
    float* __restrict__ out)
{
    int b = blockIdx.x;
    int j = threadIdx.x;
    __shared__ float vs[Hh], ms[Hh], gs[Hh], g2[Hh];
    float vp = 0.f, mp = 0.f;
    #pragma unroll
    for (int p = 0; p < 8; ++p) {
        long o = ((long)b * 8 + p) * Hh + j;
        vp += vpart[o];
        mp += mpart[o];
    }
    vs[j] = vp * (1.0f / (float)Nn);
    ms[j] = mp * (1.0f / (float)Nn);
    __syncthreads();
    float s = brel2[j];
    for (int c = 0; c < Hh; ++c)
        s += vs[c] * Wrel2[c * Hh + j] + ms[c] * Wroot2[c * Hh + j];
    gs[j] = s;
    __syncthreads();
    float t = b1[j];
    for (int k = 0; k < Hh; ++k) t += gs[k] * W1[k * Hh + j];
    g2[j] = fmaxf(t, 0.f);
    __syncthreads();
    if (j < OUTD) {
        float s2 = bout[j];
        for (int k = 0; k < Hh; ++k) s2 += g2[k] * Wout[k * OUTD + j];
        out[b * OUTD + j] = s2;
    }
}

extern "C" void kernel_launch(void* const* d_in, const int* in_sizes, int n_in,
                              void* d_out, int out_size, void* d_ws, size_t ws_size,
                              hipStream_t stream) {
    const float* x      = (const float*)d_in[0];
    const float* sigma  = (const float*)d_in[4];
    const float* Wg     = (const float*)d_in[5];
    const float* bg     = (const float*)d_in[6];
    const float* Wrel0  = (const float*)d_in[7];
    const float* Wroot0 = (const float*)d_in[8];
    const float* brel0  = (const float*)d_in[9];
    const float* Wrel1  = (const float*)d_in[10];
    const float* Wroot1 = (const float*)d_in[11];
    const float* brel1  = (const float*)d_in[12];
    const float* Wrel2  = (const float*)d_in[13];
    const float* Wroot2 = (const float*)d_in[14];
    const float* brel2  = (const float*)d_in[15];
    const float* W1     = (const float*)d_in[16];
    const float* b1     = (const float*)d_in[17];
    const float* Wout   = (const float*)d_in[18];
    const float* bout   = (const float*)d_in[19];
    float* out = (float*)d_out;

    // Workspace layout (bytes)
    char* ws = (char*)d_ws;
    unsigned short* WgT  = (unsigned short*)(ws + 0);              // 32 KB
    unsigned short* h0b  = (unsigned short*)(ws + 16777216);       // 8 MB
    unsigned short* h0T  = (unsigned short*)(ws + 25165824);       // 8 MB
    float*          sq   = (float*)(ws + 33554432);                // 128 KB
    unsigned short* Aadj = (unsigned short*)(ws + 33685504);       // 32 MB
    unsigned short* agg  = (unsigned short*)(ws + 67239936);       // 16 MB
    unsigned short* h1b  = (unsigned short*)(ws + 84017152);       // 16 MB
    unsigned short* h1T  = (unsigned short*)(ws + 100794368);      // 16 MB
    unsigned short* h2b  = (unsigned short*)(ws + 117571584);      // 16 MB
    unsigned short* WrelT0  = (unsigned short*)(ws + 167903232);   // 64 KB
    unsigned short* WrootT0 = (unsigned short*)(ws + 167968768);   // 64 KB
    unsigned short* WrelT1  = (unsigned short*)(ws + 168034304);   // 128 KB
    unsigned short* WrootT1 = (unsigned short*)(ws + 168165376);   // 128 KB
    float*          w     = (float*)(ws + 168558592);              // 128 KB (A row sums)
    float*          vpart = (float*)(ws + 168689664);              // 512 KB
    float*          mpart = (float*)(ws + 169213952);              // 512 KB

    // prep (weights + w zero) and h0 in one dispatch
    prep_h0<<<1216, 256, 0, stream>>>(x, Wg, bg, Wrel0, Wroot0, Wrel1, Wroot1,
                                      WrelT0, WrootT0, WrelT1, WrootT1, WgT,
                                      w, h0b, h0T, sq);

    // A = exp(-dist/(2 sigma^2)), zero diag; accumulate row sums w (XCD-swizzled 1D)
    gram_A_mfma<<<dim3(16 * Bsz, 1, 1), 512, 0, stream>>>(h0b, sq, sigma, Aadj, w);

    // ---- layer 0 ----
    gemm_bf16<<<dim3(4 * Bsz, 1, 1), 512, 0, stream>>>(
        Aadj, h0T, nullptr, nullptr, nullptr, agg, nullptr,
        Nn, Ff, Nn, 0,
        (long)Nn * Nn, (long)Ff * Nn, (long)Nn * Ff, 8);
    gemm_bf16<<<dim3(MTOT / 128, Hh / 128, 1), 512, 0, stream>>>(
        agg, WrelT0, h0b, WrootT0, brel0, h1b, h1T,
        MTOT, Hh, Ff, Ff, 0, 0, 0, 1);

    // ---- layer 1 ----
    gemm_bf16<<<dim3(8 * Bsz, 1, 1), 512, 0, stream>>>(
        Aadj, h1T, nullptr, nullptr, nullptr, agg, nullptr,
        Nn, Hh, Nn, 0,
        (long)Nn * Nn, (long)Hh * Nn, (long)Nn * Hh, 8);
    gemm_bf16<<<dim3(MTOT / 128, Hh / 128, 1), 512, 0, stream>>>(
        agg, WrelT1, h1b, WrootT1, brel1, h2b, nullptr,
        MTOT, Hh, Hh, Hh, 0, 0, 0, 1);

    // ---- layer 2 collapsed: partial pools (512 blocks), then head ----
    reduce_h2<<<dim3(Bsz, 8), 256, 0, stream>>>(h2b, w, vpart, mpart);
    head_kernel<<<Bsz, 256, 0, stream>>>(vpart, mpart, Wrel2, Wroot2, brel2,
                                         W1, b1, Wout, bout, out);
}

// Round 11
// 233.961 us; speedup vs baseline: 1.0614x; 1.0104x over previous
//
#include <hip/hip_runtime.h>
#include <math.h>

// Problem constants
#define Bsz 64
#define Nn 512
#define Ff 128
#define Hh 256
#define OUTD 6
#define MTOT (Bsz * Nn)   // 32768

typedef __bf16 bf16x8 __attribute__((ext_vector_type(8)));
typedef float f32x4 __attribute__((ext_vector_type(4)));
typedef int int4v __attribute__((ext_vector_type(4)));
typedef unsigned short ushort4v __attribute__((ext_vector_type(4)));

__device__ __forceinline__ unsigned short f2bf(float f) {
    unsigned u = __float_as_uint(f);
    u += 0x7FFFu + ((u >> 16) & 1u);        // RNE
    return (unsigned short)(u >> 16);
}
__device__ __forceinline__ float bf2f(unsigned short s) {
    return __uint_as_float(((unsigned)s) << 16);
}

// XOR swizzle of the 16B k-chunk within a 64B LDS row (kills ds_read_b128 bank conflicts)
#define SWZ(r) (((r) ^ ((r) >> 2)) & 3)

// async 16B global->LDS (DMA; LDS dest = wave-uniform base + lane*16)
__device__ __forceinline__ void async_ld16(const unsigned short* g, unsigned short* l) {
    __builtin_amdgcn_global_load_lds(
        (const __attribute__((address_space(1))) void*)g,
        (__attribute__((address_space(3))) void*)l,
        16, 0, 0);
}

#define LDH 40           // padded LDS row stride (bf16) for the non-async h0 kernel
#define TSZ (128 * 32)   // one LDS tile: 128 rows x 32 bf16 (8 KB)

// ---------------- A@h GEMM (bf16 MFMA, 128x128 tile, 8 waves, dbuf) ------
// C = A0@B0; B0T[n][k]; 1D grid: graph = id&63 (XCD locality), tile = id>>6.
__global__ __launch_bounds__(512) void gemm_ah(
    const unsigned short* __restrict__ A0, const unsigned short* __restrict__ B0T,
    unsigned short* __restrict__ C,
    int Ntot, int K0,
    long strideA0, long strideB0, long strideC, int tilesPerRow)
{
    int id = blockIdx.x;
    int bz = id & 63;
    int t = id >> 6;
    int bx = t % tilesPerRow;
    int by = t / tilesPerRow;

    A0 += (long)bz * strideA0;
    B0T += (long)bz * strideB0;
    C += (long)bz * strideC;

    __shared__ unsigned short As[2 * TSZ];
    __shared__ unsigned short Bs[2 * TSZ];

    int tid = threadIdx.x;
    int lane = tid & 63;
    int wave = tid >> 6;                 // 0..7
    int quad = lane >> 4, l16 = lane & 15;
    int wm = (wave >> 1) * 32, wn = (wave & 1) * 64;   // 32x64 per wave
    int m0 = bx * 128, n0 = by * 128;

    int sr = lane >> 2, sc = lane & 3;

    int T = K0 >> 5;

    f32x4 acc[2][4] = {};

    auto issue = [&](int g) {
        int kk = g << 5;
        unsigned short* Ad = As + (g & 1) * TSZ;
        unsigned short* Bd = Bs + (g & 1) * TSZ;
        int r = wave * 16 + sr;
        int c = sc ^ SWZ(r);
        async_ld16(A0 + (long)(m0 + r) * K0 + kk + c * 8, Ad + (wave * 16) * 32);
        async_ld16(B0T + (long)(n0 + r) * K0 + kk + c * 8, Bd + (wave * 16) * 32);
    };

    issue(0);
    for (int g = 0; g < T; ++g) {
        __syncthreads();
        if (g + 1 < T) issue(g + 1);
        const unsigned short* Ab = As + (g & 1) * TSZ;
        const unsigned short* Bb = Bs + (g & 1) * TSZ;
        bf16x8 af[2], bfr[4];
        #pragma unroll
        for (int i = 0; i < 2; ++i) {
            int r = wm + i * 16 + l16;
            af[i] = *(const bf16x8*)&Ab[r * 32 + (quad ^ SWZ(r)) * 8];
        }
        #pragma unroll
        for (int j = 0; j < 4; ++j) {
            int r = wn + j * 16 + l16;
            bfr[j] = *(const bf16x8*)&Bb[r * 32 + (quad ^ SWZ(r)) * 8];
        }
        #pragma unroll
        for (int i = 0; i < 2; ++i)
            #pragma unroll
            for (int j = 0; j < 4; ++j)
                acc[i][j] = __builtin_amdgcn_mfma_f32_16x16x32_bf16(
                    af[i], bfr[j], acc[i][j], 0, 0, 0);
    }

    // epilogue: C[node][feat], col=lane&15 (feat), row=quad*4+reg (node)
    #pragma unroll
    for (int i = 0; i < 2; ++i) {
        int mb = m0 + wm + i * 16 + quad * 4;
        #pragma unroll
        for (int j = 0; j < 4; ++j) {
            int n = n0 + wn + j * 16 + l16;
            f32x4 v = acc[i][j];
            C[(long)(mb + 0) * Ntot + n] = f2bf(v[0]);
            C[(long)(mb + 1) * Ntot + n] = f2bf(v[1]);
            C[(long)(mb + 2) * Ntot + n] = f2bf(v[2]);
            C[(long)(mb + 3) * Ntot + n] = f2bf(v[3]);
        }
    }
}

// ---------------- TRANSPOSED dense GEMM --------------------------------------
// outT_math = Wrel^T@agg^T + Wroot^T@h^T + bias (per outfeat), relu.
// M = 256 outfeats (A0/A1 = WrelT/WrootT rows), N = 32768 nodes
// (B0T = agg node-major, B1T = h node-major). Bitwise identical to the
// normal-orientation dense GEMM (mul commutes, same K order).
// Stores: outB[node][feat] (packed ushort4) and optional outT[graph][feat][node].
__global__ __launch_bounds__(512) void dense_t(
    const unsigned short* __restrict__ A0, const unsigned short* __restrict__ B0T,
    const unsigned short* __restrict__ A1, const unsigned short* __restrict__ B1T,
    const float* __restrict__ bias,
    unsigned short* __restrict__ outB, unsigned short* __restrict__ outT,
    int K0, int K1, int relu)
{
    int m0 = blockIdx.x * 128;    // outfeat block (0,128)
    int n0 = blockIdx.y * 128;    // node block

    __shared__ unsigned short As[2 * TSZ];
    __shared__ unsigned short Bs[2 * TSZ];

    int tid = threadIdx.x;
    int lane = tid & 63;
    int wave = tid >> 6;
    int quad = lane >> 4, l16 = lane & 15;
    int wm = (wave >> 1) * 32, wn = (wave & 1) * 64;

    int sr = lane >> 2, sc = lane & 3;

    int T0 = K0 >> 5, T1 = K1 >> 5;
    int T = T0 + T1;

    f32x4 acc[2][4] = {};

    auto issue = [&](int g) {
        const unsigned short* Ag; const unsigned short* Bg; int Kg, kk;
        if (g < T0) { Ag = A0; Bg = B0T; Kg = K0; kk = g << 5; }
        else        { Ag = A1; Bg = B1T; Kg = K1; kk = (g - T0) << 5; }
        unsigned short* Ad = As + (g & 1) * TSZ;
        unsigned short* Bd = Bs + (g & 1) * TSZ;
        int r = wave * 16 + sr;
        int c = sc ^ SWZ(r);
        async_ld16(Ag + (long)(m0 + r) * Kg + kk + c * 8, Ad + (wave * 16) * 32);
        async_ld16(Bg + (long)(n0 + r) * Kg + kk + c * 8, Bd + (wave * 16) * 32);
    };

    issue(0);
    for (int g = 0; g < T; ++g) {
        __syncthreads();
        if (g + 1 < T) issue(g + 1);
        const unsigned short* Ab = As + (g & 1) * TSZ;
        const unsigned short* Bb = Bs + (g & 1) * TSZ;
        bf16x8 af[2], bfr[4];
        #pragma unroll
        for (int i = 0; i < 2; ++i) {
            int r = wm + i * 16 + l16;
            af[i] = *(const bf16x8*)&Ab[r * 32 + (quad ^ SWZ(r)) * 8];
        }
        #pragma unroll
        for (int j = 0; j < 4; ++j) {
            int r = wn + j * 16 + l16;
            bfr[j] = *(const bf16x8*)&Bb[r * 32 + (quad ^ SWZ(r)) * 8];
        }
        #pragma unroll
        for (int i = 0; i < 2; ++i)
            #pragma unroll
            for (int j = 0; j < 4; ++j)
                acc[i][j] = __builtin_amdgcn_mfma_f32_16x16x32_bf16(
                    af[i], bfr[j], acc[i][j], 0, 0, 0);
    }

    // epilogue: row (quad*4+reg) = outfeat, col (lane&15) = node
    #pragma unroll
    for (int i = 0; i < 2; ++i) {
        int of = m0 + wm + i * 16 + quad * 4;      // 4 consecutive outfeats
        float b0 = bias[of + 0], b1 = bias[of + 1];
        float b2 = bias[of + 2], b3 = bias[of + 3];
        #pragma unroll
        for (int j = 0; j < 4; ++j) {
            int node = n0 + wn + j * 16 + l16;
            f32x4 v = acc[i][j];
            float o0 = v[0] + b0, o1 = v[1] + b1, o2 = v[2] + b2, o3 = v[3] + b3;
            if (relu) {
                o0 = fmaxf(o0, 0.f); o1 = fmaxf(o1, 0.f);
                o2 = fmaxf(o2, 0.f); o3 = fmaxf(o3, 0.f);
            }
            ushort4v p;
            p[0] = f2bf(o0); p[1] = f2bf(o1); p[2] = f2bf(o2); p[3] = f2bf(o3);
            *(ushort4v*)&outB[(long)node * Hh + of] = p;   // packed 8B store
            if (outT) {
                long base = ((long)(node >> 9) * Hh) * 512 + (node & 511);
                outT[base + (long)(of + 0) * 512] = p[0];  // lane-coalesced 2B stores
                outT[base + (long)(of + 1) * 512] = p[1];
                outT[base + (long)(of + 2) * 512] = p[2];
                outT[base + (long)(of + 3) * 512] = p[3];
            }
        }
    }
}

// ---------------- prep: weight convert/transpose + w zero + h0 MFMA ------------
// blocks [0, 960): convert branch; blocks [960, 1216): h0 (m0 = (blk-960)*128)
__global__ __launch_bounds__(256) void prep_h0(
    const float* __restrict__ x, const float* __restrict__ Wg,
    const float* __restrict__ bg,
    const float* __restrict__ Wrel0, const float* __restrict__ Wroot0,
    const float* __restrict__ Wrel1, const float* __restrict__ Wroot1,
    unsigned short* __restrict__ T0, unsigned short* __restrict__ T1,
    unsigned short* __restrict__ T2, unsigned short* __restrict__ T3,
    unsigned short* __restrict__ WgT,
    float* __restrict__ w,
    unsigned short* __restrict__ h0b, unsigned short* __restrict__ h0T,
    float* __restrict__ sqv)
{
    if (blockIdx.x < 960) {
        int idx = blockIdx.x * 256 + threadIdx.x;    // 0..245759
        if (idx >= 212992) { w[idx - 212992] = 0.f; return; }    // w: 32768 floats
        if (idx >= 196608) {                          // WgT: [128 out][128 in]
            int e = idx - 196608;
            int o = e >> 7, i = e & 127;
            WgT[e] = f2bf(Wg[(long)i * 128 + o]);
            return;
        }
        const float* src; unsigned short* dst; int kin; int e;
        if      (idx <  32768) { src = Wrel0;  dst = T0; kin = 128; e = idx; }
        else if (idx <  65536) { src = Wroot0; dst = T1; kin = 128; e = idx - 32768; }
        else if (idx < 131072) { src = Wrel1;  dst = T2; kin = 256; e = idx - 65536; }
        else                   { src = Wroot1; dst = T3; kin = 256; e = idx - 131072; }
        int o = (kin == 128) ? (e >> 7) : (e >> 8);
        int i = e & (kin - 1);
        dst[e] = f2bf(src[(long)i * 256 + o]);       // conv out-dims are all 256
        return;
    }

    // ---- h0 branch: converts Wg on the fly (no dependency on convert blocks) ----
    __shared__ unsigned short As[128 * LDH];
    __shared__ unsigned short Bs[128 * LDH];
    __shared__ float rsq[128];

    int tid = threadIdx.x;
    int lane = tid & 63;
    int wave = tid >> 6;
    int quad = lane >> 4, l16 = lane & 15;
    int wm = (wave >> 1) * 64, wn = (wave & 1) * 64;
    int m0 = (blockIdx.x - 960) * 128;

    f32x4 acc[4][4] = {};

    for (int k0 = 0; k0 < Ff; k0 += 32) {
        __syncthreads();
        #pragma unroll
        for (int l = 0; l < 2; ++l) {
            int idx = tid + l * 256;
            int r = idx >> 2, ch = idx & 3;
            const float* px = x + (long)(m0 + r) * Ff + k0 + ch * 8;
            float4 xa = *(const float4*)px;
            float4 xb = *(const float4*)(px + 4);
            ushort4v pa, pb;
            pa[0] = f2bf(xa.x); pa[1] = f2bf(xa.y); pa[2] = f2bf(xa.z); pa[3] = f2bf(xa.w);
            pb[0] = f2bf(xb.x); pb[1] = f2bf(xb.y); pb[2] = f2bf(xb.z); pb[3] = f2bf(xb.w);
            *(ushort4v*)&As[r * LDH + ch * 8] = pa;
            *(ushort4v*)&As[r * LDH + ch * 8 + 4] = pb;
            // B = WgT[r][k] = Wg[k][r] (transpose on the fly, fp32 source)
            int kk = k0 + ch * 8;
            ushort4v qa, qb;
            #pragma unroll
            for (int u = 0; u < 4; ++u) qa[u] = f2bf(Wg[(long)(kk + u) * 128 + r]);
            #pragma unroll
            for (int u = 0; u < 4; ++u) qb[u] = f2bf(Wg[(long)(kk + 4 + u) * 128 + r]);
            *(ushort4v*)&Bs[r * LDH + ch * 8] = qa;
            *(ushort4v*)&Bs[r * LDH + ch * 8 + 4] = qb;
        }
        __syncthreads();
        bf16x8 af[4], bfr[4];
        #pragma unroll
        for (int i = 0; i < 4; ++i)
            af[i] = *(const bf16x8*)&As[(wm + i * 16 + l16) * LDH + quad * 8];
        #pragma unroll
        for (int j = 0; j < 4; ++j)
            bfr[j] = *(const bf16x8*)&Bs[(wn + j * 16 + l16) * LDH + quad * 8];
        #pragma unroll
        for (int i = 0; i < 4; ++i)
            #pragma unroll
            for (int j = 0; j < 4; ++j)
                acc[i][j] = __builtin_amdgcn_mfma_f32_16x16x32_bf16(
                    af[i], bfr[j], acc[i][j], 0, 0, 0);
    }

    if (tid < 128) rsq[tid] = 0.f;
    __syncthreads();

    #pragma unroll
    for (int i = 0; i < 4; ++i) {
        int lrow = wm + i * 16 + quad * 4;   // local row of first of 4
        int mb = m0 + lrow;
        float rp0 = 0.f, rp1 = 0.f, rp2 = 0.f, rp3 = 0.f;
        #pragma unroll
        for (int j = 0; j < 4; ++j) {
            int n = wn + j * 16 + l16;
            f32x4 v = acc[i][j];
            float bv = bg[n];
            unsigned short s0 = f2bf(v[0] + bv), s1 = f2bf(v[1] + bv);
            unsigned short s2 = f2bf(v[2] + bv), s3 = f2bf(v[3] + bv);
            h0b[(long)(mb + 0) * Ff + n] = s0;
            h0b[(long)(mb + 1) * Ff + n] = s1;
            h0b[(long)(mb + 2) * Ff + n] = s2;
            h0b[(long)(mb + 3) * Ff + n] = s3;
            ushort4v p; p[0] = s0; p[1] = s1; p[2] = s2; p[3] = s3;
            long ti = ((long)(mb >> 9) * Ff + n) * 512 + (mb & 511);
            *(ushort4v*)&h0T[ti] = p;
            float f0 = bf2f(s0), f1 = bf2f(s1), f2 = bf2f(s2), f3 = bf2f(s3);
            rp0 += f0 * f0; rp1 += f1 * f1; rp2 += f2 * f2; rp3 += f3 * f3;
        }
        #pragma unroll
        for (int m = 1; m < 16; m <<= 1) {
            rp0 += __shfl_xor(rp0, m);
            rp1 += __shfl_xor(rp1, m);
            rp2 += __shfl_xor(rp2, m);
            rp3 += __shfl_xor(rp3, m);
        }
        if (l16 == 0) {   // two waves share rows -> atomic
            atomicAdd(&rsq[lrow + 0], rp0);
            atomicAdd(&rsq[lrow + 1], rp1);
            atomicAdd(&rsq[lrow + 2], rp2);
            atomicAdd(&rsq[lrow + 3], rp3);
        }
    }
    __syncthreads();
    if (tid < 128) sqv[m0 + tid] = rsq[tid];
}

// ---------------- Gram -> adjacency A via MFMA (8 waves, dbuf; also row-sums w) -----
// 1D grid: graph = id&63, tile = id>>6 (x = t&3, y = t>>2) — XCD locality.
// A store is TRANSPOSED-packed (A symmetric, bitwise identical).
__global__ __launch_bounds__(512) void gram_A_mfma(
    const unsigned short* __restrict__ h0b, const float* __restrict__ sqv,
    const float* __restrict__ sigma, unsigned short* __restrict__ Aout,
    float* __restrict__ w)
{
    int id = blockIdx.x;
    int b = id & 63;
    int t = id >> 6;
    int i0 = (t & 3) * 128, j0 = (t >> 2) * 128;

    const unsigned short* H = h0b + (long)b * Nn * Ff;
    const float* SQ = sqv + (long)b * Nn;
    unsigned short* Ab = Aout + (long)b * Nn * Nn;

    __shared__ unsigned short Is[2 * TSZ];
    __shared__ unsigned short Js[2 * TSZ];
    __shared__ float rsum[128];

    int tid = threadIdx.x;
    int lane = tid & 63;
    int wave = tid >> 6;                 // 0..7
    int quad = lane >> 4, l16 = lane & 15;
    int wm = (wave >> 1) * 32, wn = (wave & 1) * 64;

    int sr = lane >> 2, sc = lane & 3;

    f32x4 acc[2][4] = {};

    auto issue = [&](int g) {
        int kk = g << 5;
        unsigned short* Id = Is + (g & 1) * TSZ;
        unsigned short* Jd = Js + (g & 1) * TSZ;
        int r = wave * 16 + sr;
        int c = sc ^ SWZ(r);
        async_ld16(H + (long)(i0 + r) * Ff + kk + c * 8, Id + (wave * 16) * 32);
        async_ld16(H + (long)(j0 + r) * Ff + kk + c * 8, Jd + (wave * 16) * 32);
    };

    issue(0);
    for (int g = 0; g < (Ff >> 5); ++g) {
        __syncthreads();
        if (g + 1 < (Ff >> 5)) issue(g + 1);
        const unsigned short* Ib = Is + (g & 1) * TSZ;
        const unsigned short* Jb = Js + (g & 1) * TSZ;
        bf16x8 af[2], bfr[4];
        #pragma unroll
        for (int i = 0; i < 2; ++i) {
            int r = wm + i * 16 + l16;
            af[i] = *(const bf16x8*)&Ib[r * 32 + (quad ^ SWZ(r)) * 8];
        }
        #pragma unroll
        for (int j = 0; j < 4; ++j) {
            int r = wn + j * 16 + l16;
            bfr[j] = *(const bf16x8*)&Jb[r * 32 + (quad ^ SWZ(r)) * 8];
        }
        #pragma unroll
        for (int i = 0; i < 2; ++i)
            #pragma unroll
            for (int j = 0; j < 4; ++j)
                acc[i][j] = __builtin_amdgcn_mfma_f32_16x16x32_bf16(
                    af[i], bfr[j], acc[i][j], 0, 0, 0);
    }

    if (tid < 128) rsum[tid] = 0.f;
    __syncthreads();

    float s = sigma[0];
    float inv2s2 = 1.0f / (2.0f * s * s);
    #pragma unroll
    for (int i = 0; i < 2; ++i) {
        int lrow = wm + i * 16 + quad * 4;
        int rb = i0 + lrow;
        float rs0 = 0.f, rs1 = 0.f, rs2 = 0.f, rs3 = 0.f;
        #pragma unroll
        for (int j = 0; j < 4; ++j) {
            int c = j0 + wn + j * 16 + l16;
            float sqc = SQ[c];
            f32x4 v = acc[i][j];
            ushort4v pk;
            float av[4];
            #pragma unroll
            for (int r4 = 0; r4 < 4; ++r4) {
                int r = rb + r4;
                float d = fmaxf(SQ[r] + sqc - 2.0f * v[r4], 0.0f);
                unsigned short a = (r == c) ? (unsigned short)0
                                            : f2bf(__expf(-d * inv2s2));
                pk[r4] = a;
                av[r4] = bf2f(a);
            }
            // transposed packed store (A symmetric; bitwise identical to direct store)
            *(ushort4v*)&Ab[(long)c * Nn + rb] = pk;
            rs0 += av[0]; rs1 += av[1]; rs2 += av[2]; rs3 += av[3];
        }
        #pragma unroll
        for (int m = 1; m < 16; m <<= 1) {
            rs0 += __shfl_xor(rs0, m);
            rs1 += __shfl_xor(rs1, m);
            rs2 += __shfl_xor(rs2, m);
            rs3 += __shfl_xor(rs3, m);
        }
        if (l16 == 0) {
            atomicAdd(&rsum[lrow + 0], rs0);
            atomicAdd(&rsum[lrow + 1], rs1);
            atomicAdd(&rsum[lrow + 2], rs2);
            atomicAdd(&rsum[lrow + 3], rs3);
        }
    }
    __syncthreads();
    if (tid < 128) atomicAdd(&w[(long)b * Nn + i0 + tid], rsum[tid]);
}

// ---------------- partial pool: vpart/mpart[b][chunk][c] (no atomics) ----------
__global__ __launch_bounds__(256) void reduce_h2(
    const unsigned short* __restrict__ h2b, const float* __restrict__ w,
    float* __restrict__ vpart, float* __restrict__ mpart)
{
    int b = blockIdx.x;
    int jc = blockIdx.y;        // 0..7, 64 nodes each
    int c = threadIdx.x;        // 0..255
    const unsigned short* H = h2b + ((long)b * Nn + jc * 64) * Hh + c;
    const float* wp = w + (long)b * Nn + jc * 64;
    float vp = 0.f, mp = 0.f;
    #pragma unroll 4
    for (int j = 0; j < 64; ++j) {
        float val = bf2f(H[(long)j * Hh]);
        mp += val;
        vp += wp[j] * val;
    }
    long o = ((long)b * 8 + jc) * Hh + c;
    vpart[o] = vp;
    mpart[o] = mp;
}

// ---------------- head: sum partials + layer2-collapse + mean + MLP ----------------
__global__ __launch_bounds__(256) void head_kernel(
    const float* __restrict__ vpart, const float* __restrict__ mpart,
    const float* __restrict__ Wrel2, const float* __restrict__ Wroot2,
    const float* __restrict__ brel2,
    const float* __restrict__ W1, const float* __restrict__ b1,
    const float* __restrict__ Wout, const float* __restrict__ bout,
    float* __restrict__ out)
{
    int b = blockIdx.x;
    int j = threadIdx.x;
    __shared__ float vs[Hh], ms[Hh], gs[Hh], g2[Hh];
    float vp = 0.f, mp = 0.f;
    #pragma unroll
    for (int p = 0; p < 8; ++p) {
        long o = ((long)b * 8 + p) * Hh + j;
        vp += vpart[o];
        mp += mpart[o];
    }
    vs[j] = vp * (1.0f / (float)Nn);
    ms[j] = mp * (1.0f / (float)Nn);
    __syncthreads();
    float s = brel2[j];
    for (int c = 0; c < Hh; ++c)
        s += vs[c] * Wrel2[c * Hh + j] + ms[c] * Wroot2[c * Hh + j];
    gs[j] = s;
    __syncthreads();
    float t = b1[j];
    for (int k = 0; k < Hh; ++k) t += gs[k] * W1[k * Hh + j];
    g2[j] = fmaxf(t, 0.f);
    __syncthreads();
    if (j < OUTD) {
        float s2 = bout[j];
        for (int k = 0; k < Hh; ++k) s2 += g2[k] * Wout[k * OUTD + j];
        out[b * OUTD + j] = s2;
    }
}

extern "C" void kernel_launch(void* const* d_in, const int* in_sizes, int n_in,
                              void* d_out, int out_size, void* d_ws, size_t ws_size,
                              hipStream_t stream) {
    const float* x      = (const float*)d_in[0];
    const float* sigma  = (const float*)d_in[4];
    const float* Wg     = (const float*)d_in[5];
    const float* bg     = (const float*)d_in[6];
    const float* Wrel0  = (const float*)d_in[7];
    const float* Wroot0 = (const float*)d_in[8];
    const float* brel0  = (const float*)d_in[9];
    const float* Wrel1  = (const float*)d_in[10];
    const float* Wroot1 = (const float*)d_in[11];
    const float* brel1  = (const float*)d_in[12];
    const float* Wrel2  = (const float*)d_in[13];
    const float* Wroot2 = (const float*)d_in[14];
    const float* brel2  = (const float*)d_in[15];
    const float* W1     = (const float*)d_in[16];
    const float* b1     = (const float*)d_in[17];
    const float* Wout   = (const float*)d_in[18];
    const float* bout   = (const float*)d_in[19];
    float* out = (float*)d_out;

    // Workspace layout (bytes)
    char* ws = (char*)d_ws;
    unsigned short* WgT  = (unsigned short*)(ws + 0);              // 32 KB
    unsigned short* h0b  = (unsigned short*)(ws + 16777216);       // 8 MB
    unsigned short* h0T  = (unsigned short*)(ws + 25165824);       // 8 MB
    float*          sq   = (float*)(ws + 33554432);                // 128 KB
    unsigned short* Aadj = (unsigned short*)(ws + 33685504);       // 32 MB
    unsigned short* agg  = (unsigned short*)(ws + 67239936);       // 16 MB
    unsigned short* h1b  = (unsigned short*)(ws + 84017152);       // 16 MB
    unsigned short* h1T  = (unsigned short*)(ws + 100794368);      // 16 MB
    unsigned short* h2b  = (unsigned short*)(ws + 117571584);      // 16 MB
    unsigned short* WrelT0  = (unsigned short*)(ws + 167903232);   // 64 KB
    unsigned short* WrootT0 = (unsigned short*)(ws + 167968768);   // 64 KB
    unsigned short* WrelT1  = (unsigned short*)(ws + 168034304);   // 128 KB
    unsigned short* WrootT1 = (unsigned short*)(ws + 168165376);   // 128 KB
    float*          w     = (float*)(ws + 168558592);              // 128 KB (A row sums)
    float*          vpart = (float*)(ws + 168689664);              // 512 KB
    float*          mpart = (float*)(ws + 169213952);              // 512 KB

    // prep (weights + w zero) and h0 in one dispatch
    prep_h0<<<1216, 256, 0, stream>>>(x, Wg, bg, Wrel0, Wroot0, Wrel1, Wroot1,
                                      WrelT0, WrootT0, WrelT1, WrootT1, WgT,
                                      w, h0b, h0T, sq);

    // A = exp(-dist/(2 sigma^2)), zero diag; accumulate row sums w (XCD-swizzled 1D)
    gram_A_mfma<<<dim3(16 * Bsz, 1, 1), 512, 0, stream>>>(h0b, sq, sigma, Aadj, w);

    // ---- layer 0 ----
    gemm_ah<<<dim3(4 * Bsz, 1, 1), 512, 0, stream>>>(
        Aadj, h0T, agg, Ff, Nn,
        (long)Nn * Nn, (long)Ff * Nn, (long)Nn * Ff, 4);
    dense_t<<<dim3(2, MTOT / 128), 512, 0, stream>>>(
        WrelT0, agg, WrootT0, h0b, brel0, h1b, h1T, Ff, Ff, 1);

    // ---- layer 1 ----
    gemm_ah<<<dim3(8 * Bsz, 1, 1), 512, 0, stream>>>(
        Aadj, h1T, agg, Hh, Nn,
        (long)Nn * Nn, (long)Hh * Nn, (long)Nn * Hh, 4);
    dense_t<<<dim3(2, MTOT / 128), 512, 0, stream>>>(
        WrelT1, agg, WrootT1, h1b, brel1, h2b, nullptr, Hh, Hh, 1);

    // ---- layer 2 collapsed: partial pools (512 blocks), then head ----
    reduce_h2<<<dim3(Bsz, 8), 256, 0, stream>>>(h2b, w, vpart, mpart);
    head_kernel<<<Bsz, 256, 0, stream>>>(vpart, mpart, Wrel2, Wroot2, brel2,
                                         W1, b1, Wout, bout, out);
}